// Round 17
// baseline (122.389 us; speedup 1.0000x reference)
//
#include <hip/hip_runtime.h>
#include <hip/hip_bf16.h>
#include <stdint.h>

#define BN 8192
#define DK 1024
#define NT 16         // K-steps of 64
#define NTILES 2080   // 64*65/2 upper-triangle 128x128 tiles

typedef __attribute__((ext_vector_type(4))) float f32x4;
typedef __attribute__((ext_vector_type(2))) long long2v;

#define BAR() do { asm volatile("" ::: "memory"); __builtin_amdgcn_s_barrier(); asm volatile("" ::: "memory"); } while (0)

// ---------------- prep: e4m3 copy of x (16B-chunk swizzled) + row norms ----
// In each 64B K-segment (4 chunks), logical chunk c stored at c ^ ((row>>1)&3):
// b128 reads in snn_main then hit all 32 banks per 8-lane phase.
__global__ __launch_bounds__(256) void snn_prep(const float* __restrict__ x,
                                                unsigned char* __restrict__ xb,
                                                float* __restrict__ xn,
                                                float* __restrict__ den,
                                                float* __restrict__ num,
                                                float* __restrict__ out) {
  const int row = blockIdx.x * 4 + (threadIdx.x >> 6);
  const int lane = threadIdx.x & 63;
  const float4* src = (const float4*)(x + (size_t)row * DK) + lane * 4;
  float s = 0.f;
  unsigned int pk[4];
#pragma unroll
  for (int i = 0; i < 4; ++i) {
    float4 v = src[i];
    s = fmaf(v.x, v.x, s); s = fmaf(v.y, v.y, s);
    s = fmaf(v.z, v.z, s); s = fmaf(v.w, v.w, s);
    int p01 = __builtin_amdgcn_cvt_pk_fp8_f32(v.x, v.y, 0, false);    // bytes 0,1
    pk[i] = (unsigned int)__builtin_amdgcn_cvt_pk_fp8_f32(v.z, v.w, p01, true); // bytes 2,3
  }
  const int g = lane >> 2;          // 64B segment (0..15)
  const int c = lane & 3;           // logical 16B chunk in segment
  uint4 o; o.x = pk[0]; o.y = pk[1]; o.z = pk[2]; o.w = pk[3];
  *(uint4*)(xb + (size_t)row * DK + g * 64 + ((c ^ ((row >> 1) & 3)) << 4)) = o;
#pragma unroll
  for (int m = 32; m >= 1; m >>= 1) s += __shfl_xor(s, m);
  if (lane == 0) {
    xn[row] = s;
    den[row] = 0.f;
    num[row] = 0.f;
    if (row == 0) out[0] = 0.f;
  }
}

// ---------------- main: fp8 Gram, 128^2 triangle tiles ----------------
// Double-buffered BK=64, issue-early/drain-late (vmcnt(0) AFTER the MFMA
// cluster), raw 1-barrier/iter. ~34.5 KB LDS -> 4 blocks/CU.
__global__ __launch_bounds__(256, 4) void snn_main(
    const unsigned char* __restrict__ xb, const float* __restrict__ xn,
    const int* __restrict__ y, const unsigned int* __restrict__ Tp,
    float* __restrict__ den, float* __restrict__ num) {
  __shared__ __align__(16) unsigned char As[2][128 * 64];
  __shared__ __align__(16) unsigned char Bs[2][128 * 64];
  __shared__ float xnA[128], xnB[128];
  __shared__ int yA[128], yB[128];

  const int t = threadIdx.x;
  const int lane = t & 63;
  const int w = t >> 6;
  const int wr = w >> 1, wc = w & 1;
  const int l15 = lane & 15;
  const int lg = lane >> 4;

  // ---- XCD-chunked swizzle (2080 = 8*260, bijective) + triangle decode ----
  const int bid = blockIdx.x;
  const int ts = (bid & 7) * (NTILES / 8) + (bid >> 3);
  int I = (int)(64.5f - sqrtf(64.5f * 64.5f - 2.0f * (float)ts));
  while (I > 0 && (64 * I - (I * (I - 1)) / 2) > ts) --I;
  while ((64 * (I + 1) - ((I + 1) * I) / 2) <= ts) ++I;
  const int J = I + (ts - (64 * I - (I * (I - 1)) / 2));
  const int r0 = I * 128, c0 = J * 128;
  const bool diag = (I == J);

  const unsigned int tu = *Tp;
  const float tf = (tu & 0x7f800000u) ? __uint_as_float(tu) : (float)(int)tu;

  if (t < 128) {
    xnA[t] = xn[r0 + t]; yA[t] = y[r0 + t];
    xnB[t] = xn[c0 + t]; yB[t] = y[c0 + t];
  }

  // stage one 128-row x 64B K-segment pair, LINEAR copy (xb pre-swizzled)
  auto ISSUE = [&](int buf, int kt) {
#pragma unroll
    for (int i = 0; i < 2; ++i) {
      const int linear = i * 256 + t;       // 0..511
      const int row = linear >> 2;          // 0..127
      const int cg = linear & 3;            // 16B chunk (phys order)
      const unsigned char* sa = xb + (size_t)(r0 + row) * DK + kt + cg * 16;
      const unsigned char* sb = xb + (size_t)(c0 + row) * DK + kt + cg * 16;
      __builtin_amdgcn_global_load_lds(
          (const __attribute__((address_space(1))) void*)sa,
          (__attribute__((address_space(3))) void*)(As[buf] + linear * 16), 16, 0, 0);
      __builtin_amdgcn_global_load_lds(
          (const __attribute__((address_space(1))) void*)sb,
          (__attribute__((address_space(3))) void*)(Bs[buf] + linear * 16), 16, 0, 0);
    }
  };

  f32x4 acc[4][4];
#pragma unroll
  for (int mi = 0; mi < 4; ++mi)
#pragma unroll
    for (int ni = 0; ni < 4; ++ni) acc[mi][ni] = (f32x4){0.f, 0.f, 0.f, 0.f};

  // conflict-free b128 fragment offset: phys chunk = lg ^ ((l15>>1)&3)
  const int fro = (lg ^ ((l15 >> 1) & 3)) << 4;

  // ---- prologue: stage(0) issued, PROVEN landed before first reads ----
  ISSUE(0, 0);
  asm volatile("s_waitcnt vmcnt(0)" ::: "memory");   // stage(0) + xn/y loads done
  asm volatile("s_waitcnt lgkmcnt(0)" ::: "memory"); // xn/y LDS writes done
  BAR();

#pragma unroll
  for (int T = 0; T < NT; ++T) {
    const int rd = T & 1;
    long2v aF[4], bF[4];
#pragma unroll
    for (int mi = 0; mi < 4; ++mi) {
      const int row = wr * 64 + mi * 16 + l15;
      aF[mi] = *(const long2v*)(As[rd] + row * 64 + fro);
    }
#pragma unroll
    for (int ni = 0; ni < 4; ++ni) {
      const int row = wc * 64 + ni * 16 + l15;
      bF[ni] = *(const long2v*)(Bs[rd] + row * 64 + fro);
    }
    if (T + 1 < NT) ISSUE(rd ^ 1, (T + 1) * 64);  // issue early (other buffer)
#pragma unroll
    for (int kk = 0; kk < 2; ++kk)
#pragma unroll
      for (int mi = 0; mi < 4; ++mi)
#pragma unroll
        for (int ni = 0; ni < 4; ++ni)
          acc[mi][ni] = __builtin_amdgcn_mfma_f32_16x16x32_fp8_fp8(
              aF[mi][kk], bF[ni][kk], acc[mi][ni], 0, 0, 0);
    if (T + 1 < NT) {
      asm volatile("s_waitcnt vmcnt(0)" ::: "memory");  // drain late: stage(T+1)
      BAR();  // all waves: reads(T) retired (via MFMA) and stage(T+1) landed
    }
  }

  // ---- epilogue: v = (same ? -1 : +1) * exp(-sqrt(max(d2,0))*T) ----
  // C layout: col = l15 + ni*16 + wc*64; row = lg*4+rg + mi*16 + wr*64
  float cxn[4]; int cy[4];
#pragma unroll
  for (int ni = 0; ni < 4; ++ni) {
    const int c_l = wc * 64 + ni * 16 + l15;
    cxn[ni] = xnB[c_l]; cy[ni] = yB[c_l];
  }
#pragma unroll
  for (int mi = 0; mi < 4; ++mi) {
#pragma unroll
    for (int rg = 0; rg < 4; ++rg) {
      const int row_l = wr * 64 + mi * 16 + lg * 4 + rg;
      const int rG = r0 + row_l;
      const float rxn = xnA[row_l];
      const int ry = yA[row_l];
      float u = 0.f, av = 0.f;
#pragma unroll
      for (int ni = 0; ni < 4; ++ni) {
        const int cG = c0 + wc * 64 + ni * 16 + l15;
        const float a = acc[mi][ni][rg];
        const float d2 = fmaxf(rxn + cxn[ni] - 2.0f * a, 0.f);
        const float p = (rG == cG) ? 0.f : __expf(-sqrtf(d2) * tf);
        const float v = (ry == cy[ni]) ? -p : p;
        acc[mi][ni][rg] = v;
        u += v; av += fabsf(v);
      }
#pragma unroll
      for (int mm = 8; mm >= 1; mm >>= 1) {
        u += __shfl_xor(u, mm); av += __shfl_xor(av, mm);
      }
      if (l15 == 0) {
        atomicAdd(&den[rG], av);
        atomicAdd(&num[rG], 0.5f * (av - u));
      }
    }
  }
  if (!diag) {  // column-side sums (transposed contribution)
#pragma unroll
    for (int ni = 0; ni < 4; ++ni) {
      float u = 0.f, av = 0.f;
#pragma unroll
      for (int mi = 0; mi < 4; ++mi)
#pragma unroll
        for (int rg = 0; rg < 4; ++rg) {
          const float v = acc[mi][ni][rg];
          u += v; av += fabsf(v);
        }
      u += __shfl_xor(u, 16); av += __shfl_xor(av, 16);
      u += __shfl_xor(u, 32); av += __shfl_xor(av, 32);
      if (lg == 0) {
        const int cG = c0 + wc * 64 + ni * 16 + l15;
        atomicAdd(&den[cG], av);
        atomicAdd(&num[cG], 0.5f * (av - u));
      }
    }
  }
}

// ---------------- final: loss = mean(log den - log num), 32 blocks ----------------
__global__ __launch_bounds__(256) void snn_final(const float* __restrict__ den,
                                                 const float* __restrict__ num,
                                                 float* __restrict__ out) {
  __shared__ float red[256];
  const int t = threadIdx.x;
  const int r = blockIdx.x * 256 + t;   // 32*256 == BN exactly
  const float sd = den[r], sn = num[r];
  const float d = logf(sd);
  const float n = (sn > 0.f) ? logf(sn) : 0.f;  // no positives -> num = 0 fixup
  red[t] = d - n;
  __syncthreads();
  for (int s = 128; s >= 1; s >>= 1) {
    if (t < s) red[t] += red[t + s];
    __syncthreads();
  }
  if (t == 0) atomicAdd(out, red[0] * (1.0f / (float)BN));
}

extern "C" void kernel_launch(void* const* d_in, const int* in_sizes, int n_in,
                              void* d_out, int out_size, void* d_ws, size_t ws_size,
                              hipStream_t stream) {
  const float* x = (const float*)d_in[0];
  const int* y = (const int*)d_in[1];
  const unsigned int* Tp = (const unsigned int*)d_in[2];
  float* out = (float*)d_out;

  char* ws = (char*)d_ws;
  unsigned char* xb = (unsigned char*)ws;               // 8 MB fp8 x (swizzled)
  float* xn = (float*)(ws + (size_t)BN * DK);           // 32 KB norms
  float* den = xn + BN;                                 // 32 KB
  float* num = den + BN;                                // 32 KB

  snn_prep<<<dim3(BN / 4), dim3(256), 0, stream>>>(x, xb, xn, den, num, out);
  snn_main<<<dim3(NTILES), dim3(256), 0, stream>>>(xb, xn, y, Tp, den, num);
  snn_final<<<dim3(32), dim3(256), 0, stream>>>(den, num, out);
}

// Round 18
// 102.259 us; speedup vs baseline: 1.1969x; 1.1969x over previous
//
#include <hip/hip_runtime.h>
#include <hip/hip_bf16.h>
#include <stdint.h>

#define BN 8192
#define DK 1024
#define NT 16         // K-steps of 64
#define NTILES 2080   // 64*65/2 upper-triangle 128x128 tiles

typedef __attribute__((ext_vector_type(4))) float f32x4;
typedef __attribute__((ext_vector_type(2))) long long2v;

#define BAR() do { asm volatile("" ::: "memory"); __builtin_amdgcn_s_barrier(); asm volatile("" ::: "memory"); } while (0)

// ---------------- prep: e4m3 copy of x (16B-chunk swizzled) + row norms ----
// In each 64B K-segment (4 chunks), logical chunk c stored at c ^ ((row>>1)&3):
// b128 reads in snn_main then hit all 32 banks per 8-lane phase.
__global__ __launch_bounds__(256) void snn_prep(const float* __restrict__ x,
                                                unsigned char* __restrict__ xb,
                                                float* __restrict__ xn,
                                                float* __restrict__ den,
                                                float* __restrict__ num,
                                                float* __restrict__ out) {
  const int row = blockIdx.x * 4 + (threadIdx.x >> 6);
  const int lane = threadIdx.x & 63;
  const float4* src = (const float4*)(x + (size_t)row * DK) + lane * 4;
  float s = 0.f;
  unsigned int pk[4];
#pragma unroll
  for (int i = 0; i < 4; ++i) {
    float4 v = src[i];
    s = fmaf(v.x, v.x, s); s = fmaf(v.y, v.y, s);
    s = fmaf(v.z, v.z, s); s = fmaf(v.w, v.w, s);
    int p01 = __builtin_amdgcn_cvt_pk_fp8_f32(v.x, v.y, 0, false);    // bytes 0,1
    pk[i] = (unsigned int)__builtin_amdgcn_cvt_pk_fp8_f32(v.z, v.w, p01, true); // bytes 2,3
  }
  const int g = lane >> 2;          // 64B segment (0..15)
  const int c = lane & 3;           // logical 16B chunk in segment
  uint4 o; o.x = pk[0]; o.y = pk[1]; o.z = pk[2]; o.w = pk[3];
  *(uint4*)(xb + (size_t)row * DK + g * 64 + ((c ^ ((row >> 1) & 3)) << 4)) = o;
#pragma unroll
  for (int m = 32; m >= 1; m >>= 1) s += __shfl_xor(s, m);
  if (lane == 0) {
    xn[row] = s;
    den[row] = 0.f;
    num[row] = 0.f;
    if (row == 0) out[0] = 0.f;
  }
}

// ---------------- main: fp8 Gram, 128^2 triangle tiles ----------------
// Triple-buffered BK=64 (2-iteration prefetch distance), counted vmcnt,
// raw 1-barrier/iter. 50 KB LDS -> 3 blocks/CU. Measured local optimum.
__global__ __launch_bounds__(256, 3) void snn_main(
    const unsigned char* __restrict__ xb, const float* __restrict__ xn,
    const int* __restrict__ y, const unsigned int* __restrict__ Tp,
    float* __restrict__ den, float* __restrict__ num) {
  __shared__ __align__(16) unsigned char As[3][128 * 64];
  __shared__ __align__(16) unsigned char Bs[3][128 * 64];
  __shared__ float xnA[128], xnB[128];
  __shared__ int yA[128], yB[128];

  const int t = threadIdx.x;
  const int lane = t & 63;
  const int w = t >> 6;
  const int wr = w >> 1, wc = w & 1;
  const int l15 = lane & 15;
  const int lg = lane >> 4;

  // ---- XCD-chunked swizzle (2080 = 8*260, bijective) + triangle decode ----
  const int bid = blockIdx.x;
  const int ts = (bid & 7) * (NTILES / 8) + (bid >> 3);
  int I = (int)(64.5f - sqrtf(64.5f * 64.5f - 2.0f * (float)ts));
  while (I > 0 && (64 * I - (I * (I - 1)) / 2) > ts) --I;
  while ((64 * (I + 1) - ((I + 1) * I) / 2) <= ts) ++I;
  const int J = I + (ts - (64 * I - (I * (I - 1)) / 2));
  const int r0 = I * 128, c0 = J * 128;
  const bool diag = (I == J);

  const unsigned int tu = *Tp;
  const float tf = (tu & 0x7f800000u) ? __uint_as_float(tu) : (float)(int)tu;

  // xn/y loads BEFORE staging so loop vmcnt counts see only stage ops
  if (t < 128) {
    xnA[t] = xn[r0 + t]; yA[t] = y[r0 + t];
    xnB[t] = xn[c0 + t]; yB[t] = y[c0 + t];
  }

  // stage one 128-row x 64B K-segment pair, LINEAR copy (xb pre-swizzled)
  auto ISSUE = [&](int buf, int kt) {
#pragma unroll
    for (int i = 0; i < 2; ++i) {
      const int linear = i * 256 + t;       // 0..511
      const int row = linear >> 2;          // 0..127
      const int cg = linear & 3;            // 16B chunk (phys order)
      const unsigned char* sa = xb + (size_t)(r0 + row) * DK + kt + cg * 16;
      const unsigned char* sb = xb + (size_t)(c0 + row) * DK + kt + cg * 16;
      __builtin_amdgcn_global_load_lds(
          (const __attribute__((address_space(1))) void*)sa,
          (__attribute__((address_space(3))) void*)(As[buf] + linear * 16), 16, 0, 0);
      __builtin_amdgcn_global_load_lds(
          (const __attribute__((address_space(1))) void*)sb,
          (__attribute__((address_space(3))) void*)(Bs[buf] + linear * 16), 16, 0, 0);
    }
  };

  f32x4 acc[4][4];
#pragma unroll
  for (int mi = 0; mi < 4; ++mi)
#pragma unroll
    for (int ni = 0; ni < 4; ++ni) acc[mi][ni] = (f32x4){0.f, 0.f, 0.f, 0.f};

  // conflict-free b128 fragment offset: phys chunk = lg ^ ((l15>>1)&3)
  const int fro = (lg ^ ((l15 >> 1) & 3)) << 4;

  // ---- prologue: stages 0,1 in flight; wait stage0 only ----
  ISSUE(0, 0);
  ISSUE(1, 64);
  asm volatile("s_waitcnt vmcnt(4)" ::: "memory");
  BAR();

#pragma unroll
  for (int T = 0; T < NT; ++T) {
    const int rd = T % 3;
    const int st = (T + 2) % 3;
    long2v aF[4], bF[4];
#pragma unroll
    for (int mi = 0; mi < 4; ++mi) {
      const int row = wr * 64 + mi * 16 + l15;
      aF[mi] = *(const long2v*)(As[rd] + row * 64 + fro);
    }
#pragma unroll
    for (int ni = 0; ni < 4; ++ni) {
      const int row = wc * 64 + ni * 16 + l15;
      bF[ni] = *(const long2v*)(Bs[rd] + row * 64 + fro);
    }
    if (T + 2 < NT) {
      ISSUE(st, (T + 2) * 64);
      asm volatile("s_waitcnt vmcnt(4)" ::: "memory");  // stage(T+1) landed
    } else if (T + 1 < NT) {
      asm volatile("s_waitcnt vmcnt(0)" ::: "memory");  // single tail drain
    }
#pragma unroll
    for (int kk = 0; kk < 2; ++kk)
#pragma unroll
      for (int mi = 0; mi < 4; ++mi)
#pragma unroll
        for (int ni = 0; ni < 4; ++ni)
          acc[mi][ni] = __builtin_amdgcn_mfma_f32_16x16x32_fp8_fp8(
              aF[mi][kk], bF[ni][kk], acc[mi][ni], 0, 0, 0);
    BAR();  // all waves consumed buf[rd]; next iter may read buf[(T+1)%3]
  }

  // ---- epilogue: v = (same ? -1 : +1) * exp(-sqrt(max(d2,0))*T) ----
  // C layout: col = l15 + ni*16 + wc*64; row = lg*4+rg + mi*16 + wr*64
  float cxn[4]; int cy[4];
#pragma unroll
  for (int ni = 0; ni < 4; ++ni) {
    const int c_l = wc * 64 + ni * 16 + l15;
    cxn[ni] = xnB[c_l]; cy[ni] = yB[c_l];
  }
#pragma unroll
  for (int mi = 0; mi < 4; ++mi) {
#pragma unroll
    for (int rg = 0; rg < 4; ++rg) {
      const int row_l = wr * 64 + mi * 16 + lg * 4 + rg;
      const int rG = r0 + row_l;
      const float rxn = xnA[row_l];
      const int ry = yA[row_l];
      float u = 0.f, av = 0.f;
#pragma unroll
      for (int ni = 0; ni < 4; ++ni) {
        const int cG = c0 + wc * 64 + ni * 16 + l15;
        const float a = acc[mi][ni][rg];
        const float d2 = fmaxf(rxn + cxn[ni] - 2.0f * a, 0.f);
        const float p = (rG == cG) ? 0.f : __expf(-sqrtf(d2) * tf);
        const float v = (ry == cy[ni]) ? -p : p;
        acc[mi][ni][rg] = v;
        u += v; av += fabsf(v);
      }
#pragma unroll
      for (int mm = 8; mm >= 1; mm >>= 1) {
        u += __shfl_xor(u, mm); av += __shfl_xor(av, mm);
      }
      if (l15 == 0) {
        atomicAdd(&den[rG], av);
        atomicAdd(&num[rG], 0.5f * (av - u));
      }
    }
  }
  if (!diag) {  // column-side sums (transposed contribution)
#pragma unroll
    for (int ni = 0; ni < 4; ++ni) {
      float u = 0.f, av = 0.f;
#pragma unroll
      for (int mi = 0; mi < 4; ++mi)
#pragma unroll
        for (int rg = 0; rg < 4; ++rg) {
          const float v = acc[mi][ni][rg];
          u += v; av += fabsf(v);
        }
      u += __shfl_xor(u, 16); av += __shfl_xor(av, 16);
      u += __shfl_xor(u, 32); av += __shfl_xor(av, 32);
      if (lg == 0) {
        const int cG = c0 + wc * 64 + ni * 16 + l15;
        atomicAdd(&den[cG], av);
        atomicAdd(&num[cG], 0.5f * (av - u));
      }
    }
  }
}

// ---------------- final: loss = mean(log den - log num), 32 blocks ----------------
__global__ __launch_bounds__(256) void snn_final(const float* __restrict__ den,
                                                 const float* __restrict__ num,
                                                 float* __restrict__ out) {
  __shared__ float red[256];
  const int t = threadIdx.x;
  const int r = blockIdx.x * 256 + t;   // 32*256 == BN exactly
  const float sd = den[r], sn = num[r];
  const float d = logf(sd);
  const float n = (sn > 0.f) ? logf(sn) : 0.f;  // no positives -> num = 0 fixup
  red[t] = d - n;
  __syncthreads();
  for (int s = 128; s >= 1; s >>= 1) {
    if (t < s) red[t] += red[t + s];
    __syncthreads();
  }
  if (t == 0) atomicAdd(out, red[0] * (1.0f / (float)BN));
}

extern "C" void kernel_launch(void* const* d_in, const int* in_sizes, int n_in,
                              void* d_out, int out_size, void* d_ws, size_t ws_size,
                              hipStream_t stream) {
  const float* x = (const float*)d_in[0];
  const int* y = (const int*)d_in[1];
  const unsigned int* Tp = (const unsigned int*)d_in[2];
  float* out = (float*)d_out;

  char* ws = (char*)d_ws;
  unsigned char* xb = (unsigned char*)ws;               // 8 MB fp8 x (swizzled)
  float* xn = (float*)(ws + (size_t)BN * DK);           // 32 KB norms
  float* den = xn + BN;                                 // 32 KB
  float* num = den + BN;                                // 32 KB

  snn_prep<<<dim3(BN / 4), dim3(256), 0, stream>>>(x, xb, xn, den, num, out);
  snn_main<<<dim3(NTILES), dim3(256), 0, stream>>>(xb, xn, y, Tp, den, num);
  snn_final<<<dim3(32), dim3(256), 0, stream>>>(den, num, out);
}